// Round 4
// baseline (114.888 us; speedup 1.0000x reference)
//
#include <hip/hip_runtime.h>

namespace {

constexpr int T = 512;
constexpr int K = 4;
constexpr int G = 20000;
constexpr int EPG = 3;
constexpr int B = 512;
constexpr int GB = 256;                 // g's per out-block
constexpr int NXB = (G + GB - 1) / GB;  // 79
constexpr int GPAD = NXB * GB;          // 20224
constexpr int BT = 4;                   // b's per LDS tile (32 KB)
constexpr int NYB = 16;                 // grid y
constexpr int NTILE = B / (BT * NYB);   // 8 tiles per block
constexpr float SLOPE = 0.01f;
constexpr size_t H2T_OFF = 2u << 20;    // rec at ws+0 (1.3 MB), h2T at ws+2MB

__device__ __forceinline__ float lrelu(float x) { return x > 0.0f ? x : SLOPE * x; }

// Kernel 1: h2T[t][b][k] (t = blockIdx.x so per-t params are scalar loads;
// lane = b so the 16B h2T store is perfectly coalesced).
__global__ __launch_bounds__(256) void h2t_kernel(
    const float* __restrict__ features, const float* __restrict__ w1,
    const float* __restrict__ b1, const float* __restrict__ w2,
    const float* __restrict__ b2, float* __restrict__ h2t) {
  const int t = blockIdx.x;
  const int b = blockIdx.y * 256 + threadIdx.x;
  const float f = features[(size_t)b * T + t];  // 1MB array, L2/L3-hot
  const float4 W1 = reinterpret_cast<const float4*>(w1)[t];
  const float4 B1 = reinterpret_cast<const float4*>(b1)[t];
  const float4 B2 = reinterpret_cast<const float4*>(b2)[t];
  const float h0 = lrelu(f * W1.x + B1.x);
  const float h1 = lrelu(f * W1.y + B1.y);
  const float h2 = lrelu(f * W1.z + B1.z);
  const float h3 = lrelu(f * W1.w + B1.w);
  const float4* W2 = reinterpret_cast<const float4*>(w2 + (size_t)t * (K * K));
  const float4 r0 = W2[0];
  const float4 r1 = W2[1];
  const float4 r2 = W2[2];
  const float4 r3 = W2[3];
  float4 o;
  o.x = lrelu(B2.x + h0 * r0.x + h1 * r1.x + h2 * r2.x + h3 * r3.x);
  o.y = lrelu(B2.y + h0 * r0.y + h1 * r1.y + h2 * r2.y + h3 * r3.y);
  o.z = lrelu(B2.z + h0 * r0.z + h1 * r1.z + h2 * r2.z + h3 * r3.z);
  o.w = lrelu(B2.w + h0 * r0.w + h1 * r1.w + h2 * r2.w + h3 * r3.w);
  reinterpret_cast<float4*>(h2t)[(size_t)t * B + b] = o;
}

// Prep: per-g 64B record = [w3_e0, w3_e1, w3_e2, (bias, rowoff0, rowoff1, rowoff2)]
// rowoff_e = t_e * 64 (byte offset of row t in the 32KB [t][b4][k] LDS tile).
// Pads to GPAD with zero records so the out-kernel never reads poisoned offsets.
__global__ __launch_bounds__(256) void prep_kernel(
    const float* __restrict__ w3, const float* __restrict__ b3,
    const int* __restrict__ edge, float4* __restrict__ rec) {
  const int g = blockIdx.x * 256 + threadIdx.x;  // 0..GPAD-1
  float4 a = make_float4(0.f, 0.f, 0.f, 0.f), b = a, c = a, d = a;
  if (g < G) {
    const float4* wp = reinterpret_cast<const float4*>(w3 + (size_t)g * (EPG * K));
    a = wp[0];
    b = wp[1];
    c = wp[2];
    d.x = b3[g];
    d.y = __int_as_float(edge[g * EPG + 0] * (BT * K * 4));
    d.z = __int_as_float(edge[g * EPG + 1] * (BT * K * 4));
    d.w = __int_as_float(edge[g * EPG + 2] * (BT * K * 4));
  } else {
    d.y = d.z = d.w = __int_as_float(0);
  }
  float4* o = rec + (size_t)g * 4;
  o[0] = a; o[1] = b; o[2] = c; o[3] = d;
}

// Kernel 2 v4: 256 threads = 64 g-clusters x 4 b's. 4 records/thread in regs
// (loaded once, reused over 8 b-tiles). Per tile: stage 32KB h2T slab via
// global_load_lds (lane-linear dest), then gather: 4-lane cluster reads a
// contiguous 64B LDS row -> worst 2-way bank conflict (free). Stores: 64B
// segments (16 consecutive g per b-row per wave).
__global__ __launch_bounds__(256, 4) void out_kernel_v4(
    const float* __restrict__ h2t, const float4* __restrict__ rec,
    float* __restrict__ out) {
  __shared__ float lds[BT * T * K];  // 32 KB
  const int tid = threadIdx.x;
  const int gsub = tid >> 2;  // 0..63
  const int bidx = tid & 3;
  const int wid = tid >> 6;
  const int g0 = blockIdx.x * GB;
  const int b0 = blockIdx.y * (BT * NTILE);

  // preload 4 records (64 VGPRs); 4-lane redundancy, amortized over 8 tiles
  float4 rw0[4], rw1[4], rw2[4], rm[4];
#pragma unroll
  for (int s = 0; s < 4; ++s) {
    const float4* r = rec + (size_t)(g0 + s * 64 + gsub) * 4;
    rw0[s] = r[0]; rw1[s] = r[1]; rw2[s] = r[2]; rm[s] = r[3];
  }
  int off0[4], off1[4], off2[4];
#pragma unroll
  for (int s = 0; s < 4; ++s) {
    off0[s] = __float_as_int(rm[s].y) + bidx * 16;
    off1[s] = __float_as_int(rm[s].z) + bidx * 16;
    off2[s] = __float_as_int(rm[s].w) + bidx * 16;
  }

  const char* ldsc = reinterpret_cast<const char*>(lds);

  for (int ib = 0; ib < NTILE; ++ib) {
    const int bb = b0 + ib * BT;
    // stage: 8 x 16B global_load_lds per thread; LDS dest byte = (j*256+tid)*16
    // (lane-linear), global src = h2t[t][bb+b] with t=idx>>2, b=idx&3.
#pragma unroll
    for (int j = 0; j < 8; ++j) {
      const int idx = j * 256 + tid;
      const int t = idx >> 2;
      const int b = idx & 3;
      const float* src = h2t + ((size_t)t * B + bb + b) * 4;
      char* dst = reinterpret_cast<char*>(lds) + (j * 256 + wid * 64) * 16;
      __builtin_amdgcn_global_load_lds(
          (const __attribute__((address_space(1))) void*)src,
          (__attribute__((address_space(3))) void*)dst, 16, 0, 0);
    }
    asm volatile("s_waitcnt vmcnt(0)" ::: "memory");
    __syncthreads();

#pragma unroll
    for (int s = 0; s < 4; ++s) {
      const float4 v0 = *reinterpret_cast<const float4*>(ldsc + off0[s]);
      const float4 v1 = *reinterpret_cast<const float4*>(ldsc + off1[s]);
      const float4 v2 = *reinterpret_cast<const float4*>(ldsc + off2[s]);
      float a = rm[s].x;
      a += v0.x * rw0[s].x + v0.y * rw0[s].y + v0.z * rw0[s].z + v0.w * rw0[s].w;
      a += v1.x * rw1[s].x + v1.y * rw1[s].y + v1.z * rw1[s].z + v1.w * rw1[s].w;
      a += v2.x * rw2[s].x + v2.y * rw2[s].y + v2.z * rw2[s].z + v2.w * rw2[s].w;
      const int g = g0 + s * 64 + gsub;
      if (g < G) out[(size_t)(bb + bidx) * G + g] = a;
    }
    __syncthreads();  // protect lds before next tile's stage
  }
}

}  // namespace

extern "C" void kernel_launch(void* const* d_in, const int* in_sizes, int n_in,
                              void* d_out, int out_size, void* d_ws, size_t ws_size,
                              hipStream_t stream) {
  const float* features = (const float*)d_in[0];
  const float* w1 = (const float*)d_in[1];
  const float* b1 = (const float*)d_in[2];
  const float* w2 = (const float*)d_in[3];
  const float* b2 = (const float*)d_in[4];
  const float* w3 = (const float*)d_in[5];
  const float* b3 = (const float*)d_in[6];
  const int* edge = (const int*)d_in[7];
  float* out = (float*)d_out;

  float4* rec = (float4*)d_ws;                   // GPAD*64 B = 1.29 MB
  float* h2t = (float*)((char*)d_ws + H2T_OFF);  // 4 MB

  dim3 g1(T, B / 256);  // (512, 2)
  h2t_kernel<<<g1, 256, 0, stream>>>(features, w1, b1, w2, b2, h2t);

  prep_kernel<<<GPAD / 256, 256, 0, stream>>>(w3, b3, edge, rec);

  dim3 g2(NXB, NYB);  // (79, 16); x-fast dispatch -> all XCDs share one b-slab
  out_kernel_v4<<<g2, 256, 0, stream>>>(h2t, rec, out);
}

// Round 6
// 100.172 us; speedup vs baseline: 1.1469x; 1.1469x over previous
//
#include <hip/hip_runtime.h>

namespace {

constexpr int T = 512;
constexpr int K = 4;
constexpr int G = 20000;
constexpr int EPG = 3;
constexpr int B = 512;
constexpr int BT = 4;                    // b's per slab
constexpr int NSLAB = B / BT;            // 128 (grid x, fast dim)
constexpr int NG = 8;                    // g-splits (grid y, slow dim)
constexpr int GPB = 2560;                // g's per block (NG*GPB = 20480 = GPAD)
constexpr int GPAD = NG * GPB;           // 20480
constexpr int NCHUNK = GPB / 256;        // 10
constexpr int ROWSTRIDE = 20;            // dwords per t-row in LDS (80 B)
constexpr float SLOPE = 0.01f;
constexpr size_t H2T_OFF = 2u << 20;     // rec at ws+0 (1.31 MB), h2T at ws+2MB

__device__ __forceinline__ float lrelu(float x) { return x > 0.0f ? x : SLOPE * x; }
__device__ __forceinline__ float dot4(float4 a, float4 b) {
  return a.x * b.x + a.y * b.y + a.z * b.z + a.w * b.w;
}

// Kernel 1: h2T[t][b][k] (t = blockIdx.x -> per-t params are scalar loads;
// lane = b -> 16B coalesced h2T stores).
__global__ __launch_bounds__(256) void h2t_kernel(
    const float* __restrict__ features, const float* __restrict__ w1,
    const float* __restrict__ b1, const float* __restrict__ w2,
    const float* __restrict__ b2, float* __restrict__ h2t) {
  const int t = blockIdx.x;
  const int b = blockIdx.y * 256 + threadIdx.x;
  const float f = features[(size_t)b * T + t];  // 1MB array, L2-hot
  const float4 W1 = reinterpret_cast<const float4*>(w1)[t];
  const float4 B1 = reinterpret_cast<const float4*>(b1)[t];
  const float4 B2 = reinterpret_cast<const float4*>(b2)[t];
  const float h0 = lrelu(f * W1.x + B1.x);
  const float h1 = lrelu(f * W1.y + B1.y);
  const float h2 = lrelu(f * W1.z + B1.z);
  const float h3 = lrelu(f * W1.w + B1.w);
  const float4* W2 = reinterpret_cast<const float4*>(w2 + (size_t)t * (K * K));
  const float4 r0 = W2[0];
  const float4 r1 = W2[1];
  const float4 r2 = W2[2];
  const float4 r3 = W2[3];
  float4 o;
  o.x = lrelu(B2.x + h0 * r0.x + h1 * r1.x + h2 * r2.x + h3 * r3.x);
  o.y = lrelu(B2.y + h0 * r0.y + h1 * r1.y + h2 * r2.y + h3 * r3.y);
  o.z = lrelu(B2.z + h0 * r0.z + h1 * r1.z + h2 * r2.z + h3 * r3.z);
  o.w = lrelu(B2.w + h0 * r0.w + h1 * r1.w + h2 * r2.w + h3 * r3.w);
  reinterpret_cast<float4*>(h2t)[(size_t)t * B + b] = o;
}

// Prep: per-g 64B record = [w3_e0, w3_e1, w3_e2, (bias, rowbyte0, rowbyte1, rowbyte2)]
// rowbyte_e = t_e * 80 (byte offset of row t in the 40KB slab). Pads to GPAD
// with zero records (offset 0 -> safe reads; stores guarded by g<G).
__global__ __launch_bounds__(256) void prep_kernel(
    const float* __restrict__ w3, const float* __restrict__ b3,
    const int* __restrict__ edge, float4* __restrict__ rec) {
  const int g = blockIdx.x * 256 + threadIdx.x;  // 0..GPAD-1
  float4 a = make_float4(0.f, 0.f, 0.f, 0.f), b = a, c = a, d = a;
  if (g < G) {
    const float4* wp = reinterpret_cast<const float4*>(w3 + (size_t)g * (EPG * K));
    a = wp[0];
    b = wp[1];
    c = wp[2];
    d.x = b3[g];
    d.y = __int_as_float(edge[g * EPG + 0] * (ROWSTRIDE * 4));
    d.z = __int_as_float(edge[g * EPG + 1] * (ROWSTRIDE * 4));
    d.w = __int_as_float(edge[g * EPG + 2] * (ROWSTRIDE * 4));
  } else {
    d.y = d.z = d.w = __int_as_float(0);
  }
  float4* o = rec + (size_t)g * 4;
  o[0] = a; o[1] = b; o[2] = c; o[3] = d;
}

// Kernel 2 v5: block = (slab of 4 b's) x (2560 g's). Slab staged ONCE into
// 40KB LDS (stride 80B -> gather bank-windows tile all 32 banks), then 10
// barrier-free chunks: thread owns g -> coalesced rec loads (pipelined),
// 12 ds_read_b128 gather, 4 coalesced 256B out stores.
__global__ __launch_bounds__(256, 4) void out_kernel_v5(
    const float* __restrict__ h2t, const float4* __restrict__ rec,
    float* __restrict__ out) {
  __shared__ float lds[T * ROWSTRIDE];  // 40 KB
  const int tid = threadIdx.x;
  const int b0 = blockIdx.x * BT;       // slab (fast dim -> rec window L2-hot)
  const int gbase = blockIdx.y * GPB;

  // stage slab once: coalesced-ish 64B-segment reads, near-conflict-free writes
#pragma unroll
  for (int it = 0; it < (T * BT) / 256; ++it) {  // 8 iters
    const int flat = it * 256 + tid;
    const int t = flat >> 2;
    const int b = flat & 3;
    const float4 v = reinterpret_cast<const float4*>(h2t)[(size_t)t * B + b0 + b];
    *reinterpret_cast<float4*>(&lds[t * ROWSTRIDE + b * 4]) = v;
  }
  __syncthreads();  // the only barrier in the kernel

  const char* ldsc = reinterpret_cast<const char*>(lds);

  float4 p0, p1, p2, p3;
  {
    const float4* r = rec + (size_t)(gbase + tid) * 4;
    p0 = r[0]; p1 = r[1]; p2 = r[2]; p3 = r[3];
  }
  for (int s = 0; s < NCHUNK; ++s) {
    const float4 c0 = p0, c1 = p1, c2 = p2, c3 = p3;
    const int g = gbase + s * 256 + tid;
    if (s + 1 < NCHUNK) {
      const float4* r = rec + (size_t)(gbase + (s + 1) * 256 + tid) * 4;
      p0 = r[0]; p1 = r[1]; p2 = r[2]; p3 = r[3];
    }
    const int o0 = __float_as_int(c3.y);
    const int o1 = __float_as_int(c3.z);
    const int o2 = __float_as_int(c3.w);
    float a0 = c3.x, a1 = c3.x, a2 = c3.x, a3 = c3.x;
    {
      const float4 v0 = *reinterpret_cast<const float4*>(ldsc + o0);
      const float4 v1 = *reinterpret_cast<const float4*>(ldsc + o0 + 16);
      const float4 v2 = *reinterpret_cast<const float4*>(ldsc + o0 + 32);
      const float4 v3 = *reinterpret_cast<const float4*>(ldsc + o0 + 48);
      a0 += dot4(v0, c0); a1 += dot4(v1, c0); a2 += dot4(v2, c0); a3 += dot4(v3, c0);
    }
    {
      const float4 v0 = *reinterpret_cast<const float4*>(ldsc + o1);
      const float4 v1 = *reinterpret_cast<const float4*>(ldsc + o1 + 16);
      const float4 v2 = *reinterpret_cast<const float4*>(ldsc + o1 + 32);
      const float4 v3 = *reinterpret_cast<const float4*>(ldsc + o1 + 48);
      a0 += dot4(v0, c1); a1 += dot4(v1, c1); a2 += dot4(v2, c1); a3 += dot4(v3, c1);
    }
    {
      const float4 v0 = *reinterpret_cast<const float4*>(ldsc + o2);
      const float4 v1 = *reinterpret_cast<const float4*>(ldsc + o2 + 16);
      const float4 v2 = *reinterpret_cast<const float4*>(ldsc + o2 + 32);
      const float4 v3 = *reinterpret_cast<const float4*>(ldsc + o2 + 48);
      a0 += dot4(v0, c2); a1 += dot4(v1, c2); a2 += dot4(v2, c2); a3 += dot4(v3, c2);
    }
    if (g < G) {
      out[(size_t)(b0 + 0) * G + g] = a0;
      out[(size_t)(b0 + 1) * G + g] = a1;
      out[(size_t)(b0 + 2) * G + g] = a2;
      out[(size_t)(b0 + 3) * G + g] = a3;
    }
  }
}

}  // namespace

extern "C" void kernel_launch(void* const* d_in, const int* in_sizes, int n_in,
                              void* d_out, int out_size, void* d_ws, size_t ws_size,
                              hipStream_t stream) {
  const float* features = (const float*)d_in[0];
  const float* w1 = (const float*)d_in[1];
  const float* b1 = (const float*)d_in[2];
  const float* w2 = (const float*)d_in[3];
  const float* b2 = (const float*)d_in[4];
  const float* w3 = (const float*)d_in[5];
  const float* b3 = (const float*)d_in[6];
  const int* edge = (const int*)d_in[7];
  float* out = (float*)d_out;

  float4* rec = (float4*)d_ws;                   // GPAD*64 B = 1.31 MB
  float* h2t = (float*)((char*)d_ws + H2T_OFF);  // 4 MB

  dim3 g1(T, B / 256);  // (512, 2)
  h2t_kernel<<<g1, 256, 0, stream>>>(features, w1, b1, w2, b2, h2t);

  prep_kernel<<<GPAD / 256, 256, 0, stream>>>(w3, b3, edge, rec);

  dim3 g2(NSLAB, NG);  // (128, 8): slab fast -> all XCDs walk same rec window
  out_kernel_v5<<<g2, 256, 0, stream>>>(h2t, rec, out);
}

// Round 7
// 92.519 us; speedup vs baseline: 1.2418x; 1.0827x over previous
//
#include <hip/hip_runtime.h>

namespace {

constexpr int T = 512;
constexpr int K = 4;
constexpr int G = 20000;
constexpr int EPG = 3;
constexpr int B = 512;
constexpr int BT = 4;                  // b's per slab
constexpr int NSLAB = B / BT;          // 128 (grid x, fast dim -> XCD round-robin)
constexpr int NG = 8;                  // g-splits (grid y, slow dim)
constexpr int GPB = 2560;              // g's per block
constexpr int NCHUNK = GPB / 256;      // 10
constexpr int RS = 20;                 // LDS row stride in dwords (80 B):
                                       // 20t mod 32 tiles all 32 banks over 8 t-residues
constexpr float SLOPE = 0.01f;

__device__ __forceinline__ float lrelu(float x) { return fmaxf(x, SLOPE * x); }
__device__ __forceinline__ float dot4(float4 a, float4 b) {
  return a.x * b.x + a.y * b.y + a.z * b.z + a.w * b.w;
}

// One fused kernel. Block = (slab of BT=4 b's) x (window of 2560 g's).
// Phase 1: compute h2[t][b][k] for the slab straight into 40KB LDS (no h2t
//   buffer, no extra launches). Thread owns t in {tid, tid+256}: param loads
//   are perfectly coalesced (w1/b1/b2 16B/lane, w2 64B/lane contiguous),
//   feature loads are 4B/lane contiguous per b-row.
// Phase 2: barrier-free g-loop; thread owns one g per chunk. Direct coalesced
//   loads of edge (12B/lane), w3 (48B/lane), b3 (4B/lane) - window is L2-hot
//   and shared across all XCDs (g-split is the slow grid dim). Gather = 12
//   ds_read_b128 from the stride-80B slab (bank-quads tile all 32 banks).
//   Stores: 4 x 256B contiguous segments per wave.
__global__ __launch_bounds__(256, 4) void fused_kernel(
    const float* __restrict__ features, const float* __restrict__ w1,
    const float* __restrict__ b1, const float* __restrict__ w2,
    const float* __restrict__ b2, const float* __restrict__ w3,
    const float* __restrict__ b3, const int* __restrict__ edge,
    float* __restrict__ out) {
  __shared__ float lds[T * RS];  // 40 KB -> 4 blocks/CU, 16 waves/CU
  const int tid = threadIdx.x;
  const int b0 = blockIdx.x * BT;
  const int gbase = blockIdx.y * GPB;

  // ---- Phase 1: h2 slab -> LDS ----
#pragma unroll
  for (int half = 0; half < 2; ++half) {
    const int t = half * 256 + tid;
    const float4 W1 = reinterpret_cast<const float4*>(w1)[t];
    const float4 B1 = reinterpret_cast<const float4*>(b1)[t];
    const float4 B2 = reinterpret_cast<const float4*>(b2)[t];
    const float4* W2 = reinterpret_cast<const float4*>(w2) + t * 4;
    const float4 r0 = W2[0];
    const float4 r1 = W2[1];
    const float4 r2 = W2[2];
    const float4 r3 = W2[3];
#pragma unroll
    for (int b = 0; b < BT; ++b) {
      const float f = features[(size_t)(b0 + b) * T + t];
      const float h0 = lrelu(f * W1.x + B1.x);
      const float h1 = lrelu(f * W1.y + B1.y);
      const float h2 = lrelu(f * W1.z + B1.z);
      const float h3 = lrelu(f * W1.w + B1.w);
      float4 o;
      o.x = lrelu(B2.x + h0 * r0.x + h1 * r1.x + h2 * r2.x + h3 * r3.x);
      o.y = lrelu(B2.y + h0 * r0.y + h1 * r1.y + h2 * r2.y + h3 * r3.y);
      o.z = lrelu(B2.z + h0 * r0.z + h1 * r1.z + h2 * r2.z + h3 * r3.z);
      o.w = lrelu(B2.w + h0 * r0.w + h1 * r1.w + h2 * r2.w + h3 * r3.w);
      *reinterpret_cast<float4*>(&lds[t * RS + b * 4]) = o;
    }
  }
  __syncthreads();  // the only barrier

  const char* ldsc = reinterpret_cast<const char*>(lds);

  // ---- Phase 2: g-loop, 1-deep software pipeline ----
  float4 pw0, pw1, pw2;
  int po0, po1, po2;
  float pb;
  auto load_chunk = [&](int s) {
    const int g = gbase + s * 256 + tid;
    if (g < G) {
      const float4* wp = reinterpret_cast<const float4*>(w3 + (size_t)g * (EPG * K));
      pw0 = wp[0];
      pw1 = wp[1];
      pw2 = wp[2];
      po0 = edge[g * EPG + 0] * (RS * 4);
      po1 = edge[g * EPG + 1] * (RS * 4);
      po2 = edge[g * EPG + 2] * (RS * 4);
      pb = b3[g];
    } else {
      pw0 = pw1 = pw2 = make_float4(0.f, 0.f, 0.f, 0.f);
      po0 = po1 = po2 = 0;
      pb = 0.f;
    }
  };
  load_chunk(0);

  for (int s = 0; s < NCHUNK; ++s) {
    const float4 c0 = pw0, c1 = pw1, c2 = pw2;
    const int o0 = po0, o1 = po1, o2 = po2;
    const float bias = pb;
    const int g = gbase + s * 256 + tid;
    if (s + 1 < NCHUNK) load_chunk(s + 1);

    float a0 = bias, a1 = bias, a2 = bias, a3 = bias;
    {
      const float4 v0 = *reinterpret_cast<const float4*>(ldsc + o0);
      const float4 v1 = *reinterpret_cast<const float4*>(ldsc + o0 + 16);
      const float4 v2 = *reinterpret_cast<const float4*>(ldsc + o0 + 32);
      const float4 v3 = *reinterpret_cast<const float4*>(ldsc + o0 + 48);
      a0 += dot4(v0, c0); a1 += dot4(v1, c0); a2 += dot4(v2, c0); a3 += dot4(v3, c0);
    }
    {
      const float4 v0 = *reinterpret_cast<const float4*>(ldsc + o1);
      const float4 v1 = *reinterpret_cast<const float4*>(ldsc + o1 + 16);
      const float4 v2 = *reinterpret_cast<const float4*>(ldsc + o1 + 32);
      const float4 v3 = *reinterpret_cast<const float4*>(ldsc + o1 + 48);
      a0 += dot4(v0, c1); a1 += dot4(v1, c1); a2 += dot4(v2, c1); a3 += dot4(v3, c1);
    }
    {
      const float4 v0 = *reinterpret_cast<const float4*>(ldsc + o2);
      const float4 v1 = *reinterpret_cast<const float4*>(ldsc + o2 + 16);
      const float4 v2 = *reinterpret_cast<const float4*>(ldsc + o2 + 32);
      const float4 v3 = *reinterpret_cast<const float4*>(ldsc + o2 + 48);
      a0 += dot4(v0, c2); a1 += dot4(v1, c2); a2 += dot4(v2, c2); a3 += dot4(v3, c2);
    }
    if (g < G) {
      out[(size_t)(b0 + 0) * G + g] = a0;
      out[(size_t)(b0 + 1) * G + g] = a1;
      out[(size_t)(b0 + 2) * G + g] = a2;
      out[(size_t)(b0 + 3) * G + g] = a3;
    }
  }
}

}  // namespace

extern "C" void kernel_launch(void* const* d_in, const int* in_sizes, int n_in,
                              void* d_out, int out_size, void* d_ws, size_t ws_size,
                              hipStream_t stream) {
  const float* features = (const float*)d_in[0];
  const float* w1 = (const float*)d_in[1];
  const float* b1 = (const float*)d_in[2];
  const float* w2 = (const float*)d_in[3];
  const float* b2 = (const float*)d_in[4];
  const float* w3 = (const float*)d_in[5];
  const float* b3 = (const float*)d_in[6];
  const int* edge = (const int*)d_in[7];
  float* out = (float*)d_out;

  dim3 grid(NSLAB, NG);  // (128, 8)
  fused_kernel<<<grid, 256, 0, stream>>>(features, w1, b1, w2, b2, w3, b3, edge,
                                         out);
}